// Round 12
// baseline (477.638 us; speedup 1.0000x reference)
//
#include <hip/hip_runtime.h>
#include <math.h>

#define NNODES 100000
#define NEDGES 500000
#define DIN 776
#define DH 128
#define NHEAD 4
#define NEG_SLOPE 0.2f
#define LN_EPS 1e-5f
#define KPAD 832
#define NT_PROJ 13

typedef __attribute__((ext_vector_type(8))) short short8v;
typedef __attribute__((ext_vector_type(4))) float f32x4;

__device__ inline unsigned int f2bf_u(float f) {
    unsigned int u = __float_as_uint(f);
    return (u + 0x7fffu + ((u >> 16) & 1u)) >> 16;  // RNE
}
__device__ inline float bf2f_lo(unsigned int u) { return __uint_as_float(u << 16); }
__device__ inline float bf2f_hi(unsigned int u) { return __uint_as_float(u & 0xffff0000u); }

#define GLDS16(g, l)                                                      \
    __builtin_amdgcn_global_load_lds(                                     \
        (const __attribute__((address_space(1))) unsigned int*)(g),       \
        (__attribute__((address_space(3))) unsigned int*)(l), 16, 0, 0)

// ========== setup: all weight conversions + cnt zero in ONE kernel ==========
__global__ __launch_bounds__(256) void setup_kernel(const float* __restrict__ Wp,
                                                    const float* __restrict__ gW1,
                                                    const float* __restrict__ gW2,
                                                    const float* __restrict__ W1,
                                                    unsigned short* __restrict__ BtP,
                                                    unsigned short* __restrict__ BtG1,
                                                    unsigned short* __restrict__ BtG2,
                                                    unsigned short* __restrict__ Bt1a,
                                                    unsigned short* __restrict__ Bt1b,
                                                    int* __restrict__ cnt) {
    const int S0 = 128 * KPAD, S = 128 * 128;
    int idx = blockIdx.x * 256 + threadIdx.x;
    if (idx < S0) {
        const int n = idx / KPAD, k = idx % KPAD;
        BtP[idx] = (k < DIN) ? (unsigned short)f2bf_u(Wp[(size_t)k * 128 + n]) : (unsigned short)0;
        return;
    }
    idx -= S0;
    if (idx < S) {
        BtG1[idx] = (unsigned short)f2bf_u(gW1[(size_t)(idx & 127) * 128 + (idx >> 7)]);
        return;
    }
    idx -= S;
    if (idx < S) {
        BtG2[idx] = (unsigned short)f2bf_u(gW2[(size_t)(idx & 127) * 128 + (idx >> 7)]);
        return;
    }
    idx -= S;
    if (idx < S) {
        Bt1a[idx] = (unsigned short)f2bf_u(W1[(size_t)(idx & 127) * 128 + (idx >> 7)]);
        return;
    }
    idx -= S;
    if (idx < S) {
        Bt1b[idx] = (unsigned short)f2bf_u(W1[(size_t)(128 + (idx & 127)) * 128 + (idx >> 7)]);
        return;
    }
    idx -= S;
    if (idx < NNODES) cnt[idx] = 0;
}

// ========== proj GEMM: C[n,128] f32 = A[n,776]fp32 @ B + bias ==========
// Double-buffered A-LDS (36.9 KB): ONE barrier per K-tile, 1-deep reg prefetch.
__global__ __launch_bounds__(256) void gemm_proj(const float* __restrict__ A,
                                                 const unsigned short* __restrict__ Bt,
                                                 const float* __restrict__ bias,
                                                 float* __restrict__ C, int nrows) {
    constexpr int LSA = 72;
    __shared__ unsigned short As[2][128 * LSA];  // 2 x 18432 B
    const int tid = threadIdx.x;
    const int row0 = blockIdx.x * 128;
    const int lane = tid & 63;
    const int wid = tid >> 6;
    const int wr = (wid >> 1) * 64, wc = (wid & 1) * 64;
    const int lrow = lane & 15, hi = lane >> 4, lk = hi * 8;

    int srowv[8], schk[8];
    bool sok[8];
#pragma unroll
    for (int i = 0; i < 8; ++i) {
        const int cid = i * 256 + tid;
        srowv[i] = cid >> 4;
        schk[i] = cid & 15;
        sok[i] = (row0 + srowv[i]) < nrows;
    }

    float4 f[8];
    auto loadA = [&](int t) {
#pragma unroll
        for (int i = 0; i < 8; ++i) {
            const int k = t * 64 + schk[i] * 4;
            f[i] = (sok[i] && (k + 4 <= DIN))
                       ? *(const float4*)(A + (size_t)(row0 + srowv[i]) * DIN + k)
                       : make_float4(0.f, 0.f, 0.f, 0.f);
        }
    };
    auto writeA = [&](int buf) {
#pragma unroll
        for (int i = 0; i < 8; ++i) {
            uint2 q;
            q.x = f2bf_u(f[i].x) | (f2bf_u(f[i].y) << 16);
            q.y = f2bf_u(f[i].z) | (f2bf_u(f[i].w) << 16);
            *(uint2*)&As[buf][srowv[i] * LSA + schk[i] * 4] = q;
        }
    };

    f32x4 acc[4][4];
#pragma unroll
    for (int m = 0; m < 4; ++m)
#pragma unroll
        for (int n = 0; n < 4; ++n) acc[m][n] = (f32x4){0.f, 0.f, 0.f, 0.f};

    auto mfma_tile = [&](int t, int buf) {
#pragma unroll
        for (int ks = 0; ks < 2; ++ks) {
            short8v a[4], b[4];
#pragma unroll
            for (int m = 0; m < 4; ++m)
                a[m] = *(const short8v*)&As[buf][(wr + m * 16 + lrow) * LSA + ks * 32 + lk];
#pragma unroll
            for (int n = 0; n < 4; ++n) {
                const int col = wc + n * 16 + lrow;
                b[n] = *(const short8v*)&Bt[(size_t)col * KPAD + t * 64 + ks * 32 + lk];
            }
#pragma unroll
            for (int m = 0; m < 4; ++m)
#pragma unroll
                for (int n = 0; n < 4; ++n)
                    acc[m][n] = __builtin_amdgcn_mfma_f32_16x16x32_bf16(a[m], b[n], acc[m][n], 0, 0, 0);
        }
    };

    loadA(0);
    writeA(0);
    __syncthreads();
    for (int t = 0; t < NT_PROJ; ++t) {
        const int cur = t & 1;
        if (t + 1 < NT_PROJ) loadA(t + 1);
        mfma_tile(t, cur);
        if (t + 1 < NT_PROJ) {
            writeA(cur ^ 1);
            __syncthreads();
        }
    }

    float bv[4];
#pragma unroll
    for (int n = 0; n < 4; ++n) bv[n] = bias[wc + n * 16 + lrow];
#pragma unroll
    for (int m = 0; m < 4; ++m) {
        const int rbase = row0 + wr + m * 16 + hi * 4;
#pragma unroll
        for (int j = 0; j < 4; ++j) {
            const int r = rbase + j;
            if (r < nrows) {
#pragma unroll
                for (int n = 0; n < 4; ++n)
                    C[(size_t)r * 128 + wc + n * 16 + lrow] = acc[m][n][j] + bv[n];
            }
        }
    }
}

// ========== K=128 GEMM (+optional fused a_s/a_d epilogue), bf16 out ==========
template<bool ASAD, bool BIAS>
__global__ __launch_bounds__(256) void gemm_k128(const unsigned short* __restrict__ Ab,
                                                 const unsigned short* __restrict__ Bt,
                                                 const float* __restrict__ bias,
                                                 const float* __restrict__ gas,
                                                 const float* __restrict__ gad,
                                                 unsigned short* __restrict__ Cb,
                                                 float* __restrict__ a_s,
                                                 float* __restrict__ a_d, int nrows) {
    __shared__ unsigned short As[128 * 128];
    const int tid = threadIdx.x, lane = tid & 63, wid = tid >> 6;
    const int row0 = blockIdx.x * 128;
    const int lrow = lane & 15, hi = lane >> 4, lk = hi * 8;
    const int wr = (wid >> 1) * 64, wc = (wid & 1) * 64;

    {   // stage A via gl_lds, source pre-swizzled (XOR row&7 on 16B slots)
        const int l4 = lane >> 4, le = lane & 15;
#pragma unroll
        for (int i = 0; i < 8; ++i) {
            const int row = wid * 32 + i * 4 + l4;
            const int kk = (le ^ ((i * 4 + l4) & 7)) << 3;
            const unsigned short* g = Ab + (size_t)(row0 + row) * 128 + kk;
            GLDS16(g, &As[wid * 4096 + i * 512]);
        }
    }
    __syncthreads();

    f32x4 acc[4][4];
#pragma unroll
    for (int m = 0; m < 4; ++m)
#pragma unroll
        for (int n = 0; n < 4; ++n) acc[m][n] = (f32x4){0.f, 0.f, 0.f, 0.f};

#pragma unroll
    for (int ks = 0; ks < 4; ++ks) {
        short8v a[4];
#pragma unroll
        for (int m = 0; m < 4; ++m) {
            const int row = wr + m * 16 + lrow;
            const int e = (ks * 32 + lk) ^ ((row & 7) << 3);
            a[m] = *(const short8v*)&As[row * 128 + e];
        }
#pragma unroll
        for (int n = 0; n < 4; ++n) {
            const int col = wc + n * 16 + lrow;
            const short8v b = *(const short8v*)&Bt[(size_t)col * 128 + ks * 32 + lk];
#pragma unroll
            for (int m = 0; m < 4; ++m)
                acc[m][n] = __builtin_amdgcn_mfma_f32_16x16x32_bf16(a[m], b, acc[m][n], 0, 0, 0);
        }
    }

#pragma unroll
    for (int m = 0; m < 4; ++m) {
        const int rbase = row0 + wr + m * 16 + hi * 4;
#pragma unroll
        for (int j = 0; j < 4; ++j) {
            const int r = rbase + j;
            if (r < nrows) {
#pragma unroll
                for (int n = 0; n < 4; ++n) {
                    const int col = wc + n * 16 + lrow;
                    const float bv = BIAS ? bias[col] : 0.f;
                    Cb[(size_t)r * 128 + col] = (unsigned short)f2bf_u(acc[m][n][j] + bv);
                }
            }
        }
    }

    if (ASAD) {
        const int h0 = (wid & 1) * 2;
        float vs[4], vd[4];
#pragma unroll
        for (int n = 0; n < 4; ++n) {
            const int ai = (h0 + (n >> 1)) * 32 + (n & 1) * 16 + lrow;
            vs[n] = gas[ai];
            vd[n] = gad[ai];
        }
#pragma unroll
        for (int m = 0; m < 4; ++m) {
#pragma unroll
            for (int j = 0; j < 4; ++j) {
                float ps0 = acc[m][0][j] * vs[0] + acc[m][1][j] * vs[1];
                float ps1 = acc[m][2][j] * vs[2] + acc[m][3][j] * vs[3];
                float pd0 = acc[m][0][j] * vd[0] + acc[m][1][j] * vd[1];
                float pd1 = acc[m][2][j] * vd[2] + acc[m][3][j] * vd[3];
#pragma unroll
                for (int o = 1; o < 16; o <<= 1) {
                    ps0 += __shfl_xor(ps0, o);
                    ps1 += __shfl_xor(ps1, o);
                    pd0 += __shfl_xor(pd0, o);
                    pd1 += __shfl_xor(pd1, o);
                }
                if (lrow == 0) {
                    const int r = row0 + wr + m * 16 + hi * 4 + j;
                    if (r < nrows) {
                        a_s[(size_t)r * 4 + h0] = ps0;
                        a_s[(size_t)r * 4 + h0 + 1] = ps1;
                        a_d[(size_t)r * 4 + h0] = pd0;
                        a_d[(size_t)r * 4 + h0 + 1] = pd1;
                    }
                }
            }
        }
    }
}

// ========== head pair GEMM: one dispatch computes Asb (with bias) and Adb ==========
__global__ __launch_bounds__(256) void gemm_k128_head(const unsigned short* __restrict__ Ab,
                                                      const unsigned short* __restrict__ Bt1,
                                                      const unsigned short* __restrict__ Bt2,
                                                      const float* __restrict__ bias1,
                                                      unsigned short* __restrict__ C1,
                                                      unsigned short* __restrict__ C2,
                                                      int nrows, int gridHalf) {
    const bool second = (int)blockIdx.x >= gridHalf;
    const unsigned short* Bt = second ? Bt2 : Bt1;
    unsigned short* Cb = second ? C2 : C1;
    const float* bias = second ? nullptr : bias1;
    const int bid = second ? (blockIdx.x - gridHalf) : blockIdx.x;

    __shared__ unsigned short As[128 * 128];
    const int tid = threadIdx.x, lane = tid & 63, wid = tid >> 6;
    const int row0 = bid * 128;
    const int lrow = lane & 15, hi = lane >> 4, lk = hi * 8;
    const int wr = (wid >> 1) * 64, wc = (wid & 1) * 64;

    {
        const int l4 = lane >> 4, le = lane & 15;
#pragma unroll
        for (int i = 0; i < 8; ++i) {
            const int row = wid * 32 + i * 4 + l4;
            const int kk = (le ^ ((i * 4 + l4) & 7)) << 3;
            const unsigned short* g = Ab + (size_t)(row0 + row) * 128 + kk;
            GLDS16(g, &As[wid * 4096 + i * 512]);
        }
    }
    __syncthreads();

    f32x4 acc[4][4];
#pragma unroll
    for (int m = 0; m < 4; ++m)
#pragma unroll
        for (int n = 0; n < 4; ++n) acc[m][n] = (f32x4){0.f, 0.f, 0.f, 0.f};

#pragma unroll
    for (int ks = 0; ks < 4; ++ks) {
        short8v a[4];
#pragma unroll
        for (int m = 0; m < 4; ++m) {
            const int row = wr + m * 16 + lrow;
            const int e = (ks * 32 + lk) ^ ((row & 7) << 3);
            a[m] = *(const short8v*)&As[row * 128 + e];
        }
#pragma unroll
        for (int n = 0; n < 4; ++n) {
            const int col = wc + n * 16 + lrow;
            const short8v b = *(const short8v*)&Bt[(size_t)col * 128 + ks * 32 + lk];
#pragma unroll
            for (int m = 0; m < 4; ++m)
                acc[m][n] = __builtin_amdgcn_mfma_f32_16x16x32_bf16(a[m], b, acc[m][n], 0, 0, 0);
        }
    }

    const bool hasBias = (bias != nullptr);
#pragma unroll
    for (int m = 0; m < 4; ++m) {
        const int rbase = row0 + wr + m * 16 + hi * 4;
#pragma unroll
        for (int j = 0; j < 4; ++j) {
            const int r = rbase + j;
            if (r < nrows) {
#pragma unroll
                for (int n = 0; n < 4; ++n) {
                    const int col = wc + n * 16 + lrow;
                    const float bv = hasBias ? bias[col] : 0.f;
                    Cb[(size_t)r * 128 + col] = (unsigned short)f2bf_u(acc[m][n][j] + bv);
                }
            }
        }
    }
}

// ---------------- first LN: h f32 -> x_t f32 + actb bf16 ----------------
__global__ __launch_bounds__(256) void ln_kernel(const float* __restrict__ in,
                                                 const float* __restrict__ g,
                                                 const float* __restrict__ b,
                                                 float* __restrict__ out,
                                                 unsigned short* __restrict__ outb, int n) {
    const int wave = (blockIdx.x * blockDim.x + threadIdx.x) >> 6;
    const int lane = threadIdx.x & 63;
    if (wave >= n) return;
    const float2 v = reinterpret_cast<const float2*>(in + (size_t)wave * 128)[lane];
    float s = v.x + v.y;
    float sq = v.x * v.x + v.y * v.y;
#pragma unroll
    for (int o = 32; o; o >>= 1) { s += __shfl_xor(s, o); sq += __shfl_xor(sq, o); }
    const float mu = s * (1.f / 128.f);
    const float var = sq * (1.f / 128.f) - mu * mu;
    const float rinv = rsqrtf(var + LN_EPS);
    const float2 gg = reinterpret_cast<const float2*>(g)[lane];
    const float2 bb = reinterpret_cast<const float2*>(b)[lane];
    float2 o2;
    o2.x = (v.x - mu) * rinv * gg.x + bb.x;
    o2.y = (v.y - mu) * rinv * gg.y + bb.y;
    reinterpret_cast<float2*>(out + (size_t)wave * 128)[lane] = o2;
    reinterpret_cast<unsigned int*>(outb + (size_t)wave * 128)[lane] =
        f2bf_u(o2.x) | (f2bf_u(o2.y) << 16);
}

// ================= CSR build =================
__global__ __launch_bounds__(256) void csr_hist(const int* __restrict__ dst,
                                                int* __restrict__ cnt, int ne, int n) {
    const int e = blockIdx.x * 256 + threadIdx.x;
    if (e >= ne + n) return;
    const int d = (e < ne) ? dst[e] : (e - ne);
    atomicAdd(&cnt[d], 1);
}

__global__ __launch_bounds__(256) void csr_scan1(const int* __restrict__ cnt,
                                                 int* __restrict__ offs,
                                                 int* __restrict__ bsum, int n) {
    __shared__ int lds[256];
    const int i = blockIdx.x * 256 + threadIdx.x;
    int v = (i < n) ? cnt[i] : 0;
    lds[threadIdx.x] = v;
    __syncthreads();
    int acc = v;
#pragma unroll
    for (int o = 1; o < 256; o <<= 1) {
        int t = (threadIdx.x >= o) ? lds[threadIdx.x - o] : 0;
        __syncthreads();
        acc += t;
        lds[threadIdx.x] = acc;
        __syncthreads();
    }
    if (i < n) offs[i] = acc - v;
    if (threadIdx.x == 255) bsum[blockIdx.x] = acc;
}

__global__ __launch_bounds__(512) void csr_scan2(int* __restrict__ bsum, int nb) {
    __shared__ int lds[512];
    const int t = threadIdx.x;
    int v = (t < nb) ? bsum[t] : 0;
    lds[t] = v;
    __syncthreads();
    int acc = v;
#pragma unroll
    for (int o = 1; o < 512; o <<= 1) {
        int x = (t >= o) ? lds[t - o] : 0;
        __syncthreads();
        acc += x;
        lds[t] = acc;
        __syncthreads();
    }
    if (t < nb) bsum[t] = acc - v;
}

__global__ __launch_bounds__(256) void csr_scan3(int* __restrict__ offs,
                                                 const int* __restrict__ bsum,
                                                 int* __restrict__ cur, int n, int total) {
    const int i = blockIdx.x * 256 + threadIdx.x;
    if (i < n) {
        const int o = offs[i] + bsum[blockIdx.x];
        offs[i] = o;
        cur[i] = o;
    }
    if (i == 0) offs[n] = total;
}

__global__ __launch_bounds__(256) void csr_scatter(const int* __restrict__ src,
                                                   const int* __restrict__ dst,
                                                   int* __restrict__ cur,
                                                   int* __restrict__ csr, int ne, int n) {
    const int e = blockIdx.x * 256 + threadIdx.x;
    if (e >= ne + n) return;
    int s, d;
    if (e < ne) { s = src[e]; d = dst[e]; } else { s = d = e - ne; }
    const int slot = atomicAdd(&cur[d], 1);
    csr[slot] = s;
}

// ========== aggregation + fused residual-LN epilogue ==========
template<int MODE>
__global__ __launch_bounds__(256) void aggr_ln_kernel(const int* __restrict__ csr,
                                                      const int* __restrict__ offs,
                                                      const float* __restrict__ a_s,
                                                      const float* __restrict__ a_d,
                                                      const unsigned short* __restrict__ hWb,
                                                      float* __restrict__ xt,
                                                      const float* __restrict__ gbias,
                                                      const float* __restrict__ g1,
                                                      const float* __restrict__ b1,
                                                      const float* __restrict__ g2,
                                                      const float* __restrict__ b2,
                                                      unsigned short* __restrict__ actb, int n) {
    const int d = (blockIdx.x * blockDim.x + threadIdx.x) >> 6;
    const int lane = threadIdx.x & 63;
    if (d >= n) return;
    const int h = lane >> 4;
    const int beg = offs[d], end = offs[d + 1];
    const float ad = a_d[(size_t)d * 4 + h];

    float z = 0.f, ax = 0.f, ay = 0.f;
    for (int c = beg; c < end; c += 64) {
        const int nj = min(64, end - c);
        const int idx = (c + lane < end) ? csr[c + lane] : 0;
        int j = 0;
        for (; j + 1 < nj; j += 2) {
            const int s0 = __shfl(idx, j);
            const int s1 = __shfl(idx, j + 1);
            const float as0 = a_s[(size_t)s0 * 4 + h];
            const float as1 = a_s[(size_t)s1 * 4 + h];
            const unsigned int u0 =
                reinterpret_cast<const unsigned int*>(hWb + (size_t)s0 * 128)[lane];
            const unsigned int u1 =
                reinterpret_cast<const unsigned int*>(hWb + (size_t)s1 * 128)[lane];
            float x0 = as0 + ad; x0 = x0 > 0.f ? x0 : NEG_SLOPE * x0;
            float x1 = as1 + ad; x1 = x1 > 0.f ? x1 : NEG_SLOPE * x1;
            const float p0 = __expf(x0);
            const float p1 = __expf(x1);
            z += p0 + p1;
            ax += p0 * bf2f_lo(u0) + p1 * bf2f_lo(u1);
            ay += p0 * bf2f_hi(u0) + p1 * bf2f_hi(u1);
        }
        if (j < nj) {
            const int s0 = __shfl(idx, j);
            float x0 = a_s[(size_t)s0 * 4 + h] + ad;
            x0 = x0 > 0.f ? x0 : NEG_SLOPE * x0;
            const float p0 = __expf(x0);
            const unsigned int u0 =
                reinterpret_cast<const unsigned int*>(hWb + (size_t)s0 * 128)[lane];
            z += p0;
            ax += p0 * bf2f_lo(u0);
            ay += p0 * bf2f_hi(u0);
        }
    }
    const float rz = 1.f / z;

    const float2 a = reinterpret_cast<const float2*>(xt + (size_t)d * 128)[lane];
    const float2 gb = reinterpret_cast<const float2*>(gbias)[lane];
    float2 v;
    v.x = a.x + ax * rz + gb.x;
    v.y = a.y + ay * rz + gb.y;
    float s = v.x + v.y, sq = v.x * v.x + v.y * v.y;
#pragma unroll
    for (int o = 32; o; o >>= 1) { s += __shfl_xor(s, o); sq += __shfl_xor(sq, o); }
    float mu = s * (1.f / 128.f);
    float rinv = rsqrtf(sq * (1.f / 128.f) - mu * mu + LN_EPS);
    const float2 gg1 = reinterpret_cast<const float2*>(g1)[lane];
    const float2 bb1 = reinterpret_cast<const float2*>(b1)[lane];
    float2 y;
    y.x = (v.x - mu) * rinv * gg1.x + bb1.x;
    y.y = (v.y - mu) * rinv * gg1.y + bb1.y;
    if (MODE == 0) {
        s = y.x + y.y; sq = y.x * y.x + y.y * y.y;
#pragma unroll
        for (int o = 32; o; o >>= 1) { s += __shfl_xor(s, o); sq += __shfl_xor(sq, o); }
        mu = s * (1.f / 128.f);
        rinv = rsqrtf(sq * (1.f / 128.f) - mu * mu + LN_EPS);
        const float2 gg2 = reinterpret_cast<const float2*>(g2)[lane];
        const float2 bb2 = reinterpret_cast<const float2*>(b2)[lane];
        float2 o2;
        o2.x = (y.x - mu) * rinv * gg2.x + bb2.x;
        o2.y = (y.y - mu) * rinv * gg2.y + bb2.y;
        reinterpret_cast<float2*>(xt + (size_t)d * 128)[lane] = o2;
        reinterpret_cast<unsigned int*>(actb + (size_t)d * 128)[lane] =
            f2bf_u(o2.x) | (f2bf_u(o2.y) << 16);
    } else {
        reinterpret_cast<unsigned int*>(actb + (size_t)d * 128)[lane] =
            f2bf_u(y.x) | (f2bf_u(y.y) << 16);
    }
}

// ------- head: 64 edges per wave, 2-edge unroll (4 gathers in flight) -------
__global__ __launch_bounds__(256) void head_kernel(const int* __restrict__ src,
                                                   const int* __restrict__ dst,
                                                   const unsigned short* __restrict__ Asb,
                                                   const unsigned short* __restrict__ Adb,
                                                   const float* __restrict__ W2,
                                                   const float* __restrict__ b2,
                                                   float* __restrict__ out, int ne) {
    const int wave = (blockIdx.x * blockDim.x + threadIdx.x) >> 6;
    const int lane = threadIdx.x & 63;
    const int e0 = wave * 64;
    if (e0 >= ne) return;
    const int nj = min(64, ne - e0);
    const bool valid = (e0 + lane) < ne;
    const int sidx = valid ? src[e0 + lane] : 0;
    const int didx = valid ? dst[e0 + lane] : 0;
    const float2 w = reinterpret_cast<const float2*>(W2)[lane];
    const float bb = b2[0];
    float outv = 0.f;
    int j = 0;
    for (; j + 1 < nj; j += 2) {
        const int s0 = __shfl(sidx, j), d0 = __shfl(didx, j);
        const int s1 = __shfl(sidx, j + 1), d1 = __shfl(didx, j + 1);
        const unsigned int ua0 =
            reinterpret_cast<const unsigned int*>(Asb + (size_t)s0 * 128)[lane];
        const unsigned int ub0 =
            reinterpret_cast<const unsigned int*>(Adb + (size_t)d0 * 128)[lane];
        const unsigned int ua1 =
            reinterpret_cast<const unsigned int*>(Asb + (size_t)s1 * 128)[lane];
        const unsigned int ub1 =
            reinterpret_cast<const unsigned int*>(Adb + (size_t)d1 * 128)[lane];
        float h00 = fmaxf(bf2f_lo(ua0) + bf2f_lo(ub0), 0.f);
        float h01 = fmaxf(bf2f_hi(ua0) + bf2f_hi(ub0), 0.f);
        float h10 = fmaxf(bf2f_lo(ua1) + bf2f_lo(ub1), 0.f);
        float h11 = fmaxf(bf2f_hi(ua1) + bf2f_hi(ub1), 0.f);
        float t0 = h00 * w.x + h01 * w.y;
        float t1 = h10 * w.x + h11 * w.y;
#pragma unroll
        for (int o = 32; o; o >>= 1) {
            t0 += __shfl_xor(t0, o);
            t1 += __shfl_xor(t1, o);
        }
        if (lane == j) outv = t0 + bb;
        if (lane == j + 1) outv = t1 + bb;
    }
    if (j < nj) {
        const int s = __shfl(sidx, j), d = __shfl(didx, j);
        const unsigned int ua =
            reinterpret_cast<const unsigned int*>(Asb + (size_t)s * 128)[lane];
        const unsigned int ub =
            reinterpret_cast<const unsigned int*>(Adb + (size_t)d * 128)[lane];
        float h0 = fmaxf(bf2f_lo(ua) + bf2f_lo(ub), 0.f);
        float h1 = fmaxf(bf2f_hi(ua) + bf2f_hi(ub), 0.f);
        float t = h0 * w.x + h1 * w.y;
#pragma unroll
        for (int o = 32; o; o >>= 1) t += __shfl_xor(t, o);
        if (lane == j) outv = t + bb;
    }
    if (valid) out[e0 + lane] = outv;
}

extern "C" void kernel_launch(void* const* d_in, const int* in_sizes, int n_in,
                              void* d_out, int out_size, void* d_ws, size_t ws_size,
                              hipStream_t stream) {
    const int N = NNODES, E = NEDGES;
    const float* x  = (const float*)d_in[0];
    const int* ei   = (const int*)d_in[1];
    const int* src  = ei;
    const int* dst  = ei + E;
    const float* Wp = (const float*)d_in[3];
    const float* bp = (const float*)d_in[4];
    const float* W1 = (const float*)d_in[5];
    const float* b1 = (const float*)d_in[6];
    const float* W2 = (const float*)d_in[7];
    const float* b2 = (const float*)d_in[8];
    const float* l1_ln_a_g = (const float*)d_in[9];
    const float* l1_ln_a_b = (const float*)d_in[10];
    const float* gW1  = (const float*)d_in[11];
    const float* gas1 = (const float*)d_in[12];
    const float* gad1 = (const float*)d_in[13];
    const float* gb1  = (const float*)d_in[14];
    const float* l1_ln_b_g = (const float*)d_in[15];
    const float* l1_ln_b_b = (const float*)d_in[16];
    const float* l2_ln_a_g = (const float*)d_in[17];
    const float* l2_ln_a_b = (const float*)d_in[18];
    const float* gW2  = (const float*)d_in[19];
    const float* gas2 = (const float*)d_in[20];
    const float* gad2 = (const float*)d_in[21];
    const float* gb2  = (const float*)d_in[22];
    const float* l2_ln_b_g = (const float*)d_in[23];
    const float* l2_ln_b_b = (const float*)d_in[24];

    float* ws = (float*)d_ws;
    float* h    = ws;                     // [N,128] f32 (proj out)
    float* xt   = h + (size_t)N * 128;    // [N,128] f32 (residual trunk)
    float* a_s  = xt + (size_t)N * 128;   // [N,4]
    float* a_d  = a_s + (size_t)N * 4;
    unsigned short* actb = (unsigned short*)(a_d + (size_t)N * 4); // [N,128] bf16
    unsigned short* hWb  = actb + (size_t)N * 128;  // [N,128] bf16
    unsigned short* Asb  = hWb + (size_t)N * 128;   // [N,128] bf16
    unsigned short* Adb  = Asb + (size_t)N * 128;   // [N,128] bf16
    unsigned short* BtP  = Adb + (size_t)N * 128;   // [128][832]
    unsigned short* BtG1 = BtP + 128 * KPAD;
    unsigned short* BtG2 = BtG1 + 128 * 128;
    unsigned short* Bt1a = BtG2 + 128 * 128;
    unsigned short* Bt1b = Bt1a + 128 * 128;
    int* cnt  = (int*)(Bt1b + 128 * 128);
    int* offs = cnt + N;
    int* bsum = offs + N + 1;
    int* csr  = bsum + 512;

    const int gemmGrid = (N + 127) / 128;
    const int lnGrid = (N + 3) / 4;
    const int edgeTot = E + N;
    const int edgeGrid = (edgeTot + 255) / 256;
    const int scanBlocks = (N + 255) / 256;
    const int aggrGrid = (N * 64 + 255) / 256;
    const int headWaves = (E + 63) / 64;
    const int headGrid = (headWaves + 3) / 4;
    const int setupTot = 128 * KPAD + 4 * 128 * 128 + N;

    setup_kernel<<<(setupTot + 255) / 256, 256, 0, stream>>>(Wp, gW1, gW2, W1, BtP, BtG1,
                                                             BtG2, Bt1a, Bt1b, cnt);
    csr_hist<<<edgeGrid, 256, 0, stream>>>(dst, cnt, E, N);
    csr_scan1<<<scanBlocks, 256, 0, stream>>>(cnt, offs, bsum, N);
    csr_scan2<<<1, 512, 0, stream>>>(bsum, scanBlocks);
    csr_scan3<<<scanBlocks, 256, 0, stream>>>(offs, bsum, cnt, N, edgeTot);
    csr_scatter<<<edgeGrid, 256, 0, stream>>>(src, dst, cnt, csr, E, N);

    // ---- input projection + first LN
    gemm_proj<<<gemmGrid, 256, 0, stream>>>(x, BtP, bp, h, N);
    ln_kernel<<<lnGrid, 256, 0, stream>>>(h, l1_ln_a_g, l1_ln_a_b, xt, actb, N);

    // ---- layer 1: GEMM(+asad) -> aggr(+LN_b1+LN_a2)
    gemm_k128<true, false><<<gemmGrid, 256, 0, stream>>>(actb, BtG1, nullptr, gas1, gad1,
                                                         hWb, a_s, a_d, N);
    aggr_ln_kernel<0><<<aggrGrid, 256, 0, stream>>>(csr, offs, a_s, a_d, hWb, xt, gb1,
                                                    l1_ln_b_g, l1_ln_b_b, l2_ln_a_g,
                                                    l2_ln_a_b, actb, N);
    // ---- layer 2
    gemm_k128<true, false><<<gemmGrid, 256, 0, stream>>>(actb, BtG2, nullptr, gas2, gad2,
                                                         hWb, a_s, a_d, N);
    aggr_ln_kernel<1><<<aggrGrid, 256, 0, stream>>>(csr, offs, a_s, a_d, hWb, xt, gb2,
                                                    l2_ln_b_g, l2_ln_b_b, nullptr,
                                                    nullptr, actb, N);

    // ---- head: fused pair of K=128 GEMMs, then per-edge MLP
    gemm_k128_head<<<2 * gemmGrid, 256, 0, stream>>>(actb, Bt1a, Bt1b, b1, Asb, Adb,
                                                     N, gemmGrid);
    head_kernel<<<headGrid, 256, 0, stream>>>(src, dst, Asb, Adb, W2, b2,
                                              (float*)d_out, E);
}

// Round 13
// 463.016 us; speedup vs baseline: 1.0316x; 1.0316x over previous
//
#include <hip/hip_runtime.h>
#include <math.h>

#define NNODES 100000
#define NEDGES 500000
#define DIN 776
#define DH 128
#define NHEAD 4
#define NEG_SLOPE 0.2f
#define LN_EPS 1e-5f
#define KPAD 832
#define NT_PROJ 13

typedef __attribute__((ext_vector_type(8))) short short8v;
typedef __attribute__((ext_vector_type(4))) float f32x4;

__device__ inline unsigned int f2bf_u(float f) {
    unsigned int u = __float_as_uint(f);
    return (u + 0x7fffu + ((u >> 16) & 1u)) >> 16;  // RNE
}
__device__ inline float bf2f_lo(unsigned int u) { return __uint_as_float(u << 16); }
__device__ inline float bf2f_hi(unsigned int u) { return __uint_as_float(u & 0xffff0000u); }

#define GLDS16(g, l)                                                      \
    __builtin_amdgcn_global_load_lds(                                     \
        (const __attribute__((address_space(1))) unsigned int*)(g),       \
        (__attribute__((address_space(3))) unsigned int*)(l), 16, 0, 0)

// ========== setup: all weight conversions + cnt zero in ONE kernel ==========
__global__ __launch_bounds__(256) void setup_kernel(const float* __restrict__ Wp,
                                                    const float* __restrict__ gW1,
                                                    const float* __restrict__ gW2,
                                                    const float* __restrict__ W1,
                                                    unsigned short* __restrict__ BtP,
                                                    unsigned short* __restrict__ BtG1,
                                                    unsigned short* __restrict__ BtG2,
                                                    unsigned short* __restrict__ Bt1a,
                                                    unsigned short* __restrict__ Bt1b,
                                                    int* __restrict__ cnt) {
    const int S0 = 128 * KPAD, S = 128 * 128;
    int idx = blockIdx.x * 256 + threadIdx.x;
    if (idx < S0) {
        const int n = idx / KPAD, k = idx % KPAD;
        BtP[idx] = (k < DIN) ? (unsigned short)f2bf_u(Wp[(size_t)k * 128 + n]) : (unsigned short)0;
        return;
    }
    idx -= S0;
    if (idx < S) {
        BtG1[idx] = (unsigned short)f2bf_u(gW1[(size_t)(idx & 127) * 128 + (idx >> 7)]);
        return;
    }
    idx -= S;
    if (idx < S) {
        BtG2[idx] = (unsigned short)f2bf_u(gW2[(size_t)(idx & 127) * 128 + (idx >> 7)]);
        return;
    }
    idx -= S;
    if (idx < S) {
        Bt1a[idx] = (unsigned short)f2bf_u(W1[(size_t)(idx & 127) * 128 + (idx >> 7)]);
        return;
    }
    idx -= S;
    if (idx < S) {
        Bt1b[idx] = (unsigned short)f2bf_u(W1[(size_t)(128 + (idx & 127)) * 128 + (idx >> 7)]);
        return;
    }
    idx -= S;
    if (idx < NNODES) cnt[idx] = 0;
}

// ========== proj GEMM: C[n,128] f32 = A[n,776]fp32 @ B + bias ==========
// Double-buffered A-LDS (36.9 KB): ONE barrier per K-tile, 1-deep reg prefetch.
__global__ __launch_bounds__(256) void gemm_proj(const float* __restrict__ A,
                                                 const unsigned short* __restrict__ Bt,
                                                 const float* __restrict__ bias,
                                                 float* __restrict__ C, int nrows) {
    constexpr int LSA = 72;
    __shared__ unsigned short As[2][128 * LSA];  // 2 x 18432 B
    const int tid = threadIdx.x;
    const int row0 = blockIdx.x * 128;
    const int lane = tid & 63;
    const int wid = tid >> 6;
    const int wr = (wid >> 1) * 64, wc = (wid & 1) * 64;
    const int lrow = lane & 15, hi = lane >> 4, lk = hi * 8;

    int srowv[8], schk[8];
    bool sok[8];
#pragma unroll
    for (int i = 0; i < 8; ++i) {
        const int cid = i * 256 + tid;
        srowv[i] = cid >> 4;
        schk[i] = cid & 15;
        sok[i] = (row0 + srowv[i]) < nrows;
    }

    float4 f[8];
    auto loadA = [&](int t) {
#pragma unroll
        for (int i = 0; i < 8; ++i) {
            const int k = t * 64 + schk[i] * 4;
            f[i] = (sok[i] && (k + 4 <= DIN))
                       ? *(const float4*)(A + (size_t)(row0 + srowv[i]) * DIN + k)
                       : make_float4(0.f, 0.f, 0.f, 0.f);
        }
    };
    auto writeA = [&](int buf) {
#pragma unroll
        for (int i = 0; i < 8; ++i) {
            uint2 q;
            q.x = f2bf_u(f[i].x) | (f2bf_u(f[i].y) << 16);
            q.y = f2bf_u(f[i].z) | (f2bf_u(f[i].w) << 16);
            *(uint2*)&As[buf][srowv[i] * LSA + schk[i] * 4] = q;
        }
    };

    f32x4 acc[4][4];
#pragma unroll
    for (int m = 0; m < 4; ++m)
#pragma unroll
        for (int n = 0; n < 4; ++n) acc[m][n] = (f32x4){0.f, 0.f, 0.f, 0.f};

    auto mfma_tile = [&](int t, int buf) {
#pragma unroll
        for (int ks = 0; ks < 2; ++ks) {
            short8v a[4], b[4];
#pragma unroll
            for (int m = 0; m < 4; ++m)
                a[m] = *(const short8v*)&As[buf][(wr + m * 16 + lrow) * LSA + ks * 32 + lk];
#pragma unroll
            for (int n = 0; n < 4; ++n) {
                const int col = wc + n * 16 + lrow;
                b[n] = *(const short8v*)&Bt[(size_t)col * KPAD + t * 64 + ks * 32 + lk];
            }
#pragma unroll
            for (int m = 0; m < 4; ++m)
#pragma unroll
                for (int n = 0; n < 4; ++n)
                    acc[m][n] = __builtin_amdgcn_mfma_f32_16x16x32_bf16(a[m], b[n], acc[m][n], 0, 0, 0);
        }
    };

    loadA(0);
    writeA(0);
    __syncthreads();
    for (int t = 0; t < NT_PROJ; ++t) {
        const int cur = t & 1;
        if (t + 1 < NT_PROJ) loadA(t + 1);
        mfma_tile(t, cur);
        if (t + 1 < NT_PROJ) {
            writeA(cur ^ 1);
            __syncthreads();
        }
    }

    float bv[4];
#pragma unroll
    for (int n = 0; n < 4; ++n) bv[n] = bias[wc + n * 16 + lrow];
#pragma unroll
    for (int m = 0; m < 4; ++m) {
        const int rbase = row0 + wr + m * 16 + hi * 4;
#pragma unroll
        for (int j = 0; j < 4; ++j) {
            const int r = rbase + j;
            if (r < nrows) {
#pragma unroll
                for (int n = 0; n < 4; ++n)
                    C[(size_t)r * 128 + wc + n * 16 + lrow] = acc[m][n][j] + bv[n];
            }
        }
    }
}

// ========== K=128 GEMM (+optional fused a_s/a_d epilogue), bf16 out ==========
template<bool ASAD, bool BIAS>
__global__ __launch_bounds__(256) void gemm_k128(const unsigned short* __restrict__ Ab,
                                                 const unsigned short* __restrict__ Bt,
                                                 const float* __restrict__ bias,
                                                 const float* __restrict__ gas,
                                                 const float* __restrict__ gad,
                                                 unsigned short* __restrict__ Cb,
                                                 float* __restrict__ a_s,
                                                 float* __restrict__ a_d, int nrows) {
    __shared__ unsigned short As[128 * 128];
    const int tid = threadIdx.x, lane = tid & 63, wid = tid >> 6;
    const int row0 = blockIdx.x * 128;
    const int lrow = lane & 15, hi = lane >> 4, lk = hi * 8;
    const int wr = (wid >> 1) * 64, wc = (wid & 1) * 64;

    {   // stage A via gl_lds, source pre-swizzled (XOR row&7 on 16B slots)
        const int l4 = lane >> 4, le = lane & 15;
#pragma unroll
        for (int i = 0; i < 8; ++i) {
            const int row = wid * 32 + i * 4 + l4;
            const int kk = (le ^ ((i * 4 + l4) & 7)) << 3;
            const unsigned short* g = Ab + (size_t)(row0 + row) * 128 + kk;
            GLDS16(g, &As[wid * 4096 + i * 512]);
        }
    }
    __syncthreads();

    f32x4 acc[4][4];
#pragma unroll
    for (int m = 0; m < 4; ++m)
#pragma unroll
        for (int n = 0; n < 4; ++n) acc[m][n] = (f32x4){0.f, 0.f, 0.f, 0.f};

#pragma unroll
    for (int ks = 0; ks < 4; ++ks) {
        short8v a[4];
#pragma unroll
        for (int m = 0; m < 4; ++m) {
            const int row = wr + m * 16 + lrow;
            const int e = (ks * 32 + lk) ^ ((row & 7) << 3);
            a[m] = *(const short8v*)&As[row * 128 + e];
        }
#pragma unroll
        for (int n = 0; n < 4; ++n) {
            const int col = wc + n * 16 + lrow;
            const short8v b = *(const short8v*)&Bt[(size_t)col * 128 + ks * 32 + lk];
#pragma unroll
            for (int m = 0; m < 4; ++m)
                acc[m][n] = __builtin_amdgcn_mfma_f32_16x16x32_bf16(a[m], b, acc[m][n], 0, 0, 0);
        }
    }

#pragma unroll
    for (int m = 0; m < 4; ++m) {
        const int rbase = row0 + wr + m * 16 + hi * 4;
#pragma unroll
        for (int j = 0; j < 4; ++j) {
            const int r = rbase + j;
            if (r < nrows) {
#pragma unroll
                for (int n = 0; n < 4; ++n) {
                    const int col = wc + n * 16 + lrow;
                    const float bv = BIAS ? bias[col] : 0.f;
                    Cb[(size_t)r * 128 + col] = (unsigned short)f2bf_u(acc[m][n][j] + bv);
                }
            }
        }
    }

    if (ASAD) {
        const int h0 = (wid & 1) * 2;
        float vs[4], vd[4];
#pragma unroll
        for (int n = 0; n < 4; ++n) {
            const int ai = (h0 + (n >> 1)) * 32 + (n & 1) * 16 + lrow;
            vs[n] = gas[ai];
            vd[n] = gad[ai];
        }
#pragma unroll
        for (int m = 0; m < 4; ++m) {
#pragma unroll
            for (int j = 0; j < 4; ++j) {
                float ps0 = acc[m][0][j] * vs[0] + acc[m][1][j] * vs[1];
                float ps1 = acc[m][2][j] * vs[2] + acc[m][3][j] * vs[3];
                float pd0 = acc[m][0][j] * vd[0] + acc[m][1][j] * vd[1];
                float pd1 = acc[m][2][j] * vd[2] + acc[m][3][j] * vd[3];
#pragma unroll
                for (int o = 1; o < 16; o <<= 1) {
                    ps0 += __shfl_xor(ps0, o);
                    ps1 += __shfl_xor(ps1, o);
                    pd0 += __shfl_xor(pd0, o);
                    pd1 += __shfl_xor(pd1, o);
                }
                if (lrow == 0) {
                    const int r = row0 + wr + m * 16 + hi * 4 + j;
                    if (r < nrows) {
                        a_s[(size_t)r * 4 + h0] = ps0;
                        a_s[(size_t)r * 4 + h0 + 1] = ps1;
                        a_d[(size_t)r * 4 + h0] = pd0;
                        a_d[(size_t)r * 4 + h0 + 1] = pd1;
                    }
                }
            }
        }
    }
}

// ---------------- first LN: h f32 -> x_t f32 + actb bf16 ----------------
__global__ __launch_bounds__(256) void ln_kernel(const float* __restrict__ in,
                                                 const float* __restrict__ g,
                                                 const float* __restrict__ b,
                                                 float* __restrict__ out,
                                                 unsigned short* __restrict__ outb, int n) {
    const int wave = (blockIdx.x * blockDim.x + threadIdx.x) >> 6;
    const int lane = threadIdx.x & 63;
    if (wave >= n) return;
    const float2 v = reinterpret_cast<const float2*>(in + (size_t)wave * 128)[lane];
    float s = v.x + v.y;
    float sq = v.x * v.x + v.y * v.y;
#pragma unroll
    for (int o = 32; o; o >>= 1) { s += __shfl_xor(s, o); sq += __shfl_xor(sq, o); }
    const float mu = s * (1.f / 128.f);
    const float var = sq * (1.f / 128.f) - mu * mu;
    const float rinv = rsqrtf(var + LN_EPS);
    const float2 gg = reinterpret_cast<const float2*>(g)[lane];
    const float2 bb = reinterpret_cast<const float2*>(b)[lane];
    float2 o2;
    o2.x = (v.x - mu) * rinv * gg.x + bb.x;
    o2.y = (v.y - mu) * rinv * gg.y + bb.y;
    reinterpret_cast<float2*>(out + (size_t)wave * 128)[lane] = o2;
    reinterpret_cast<unsigned int*>(outb + (size_t)wave * 128)[lane] =
        f2bf_u(o2.x) | (f2bf_u(o2.y) << 16);
}

// ================= CSR build =================
__global__ __launch_bounds__(256) void csr_hist(const int* __restrict__ dst,
                                                int* __restrict__ cnt, int ne, int n) {
    const int e = blockIdx.x * 256 + threadIdx.x;
    if (e >= ne + n) return;
    const int d = (e < ne) ? dst[e] : (e - ne);
    atomicAdd(&cnt[d], 1);
}

__global__ __launch_bounds__(256) void csr_scan1(const int* __restrict__ cnt,
                                                 int* __restrict__ offs,
                                                 int* __restrict__ bsum, int n) {
    __shared__ int lds[256];
    const int i = blockIdx.x * 256 + threadIdx.x;
    int v = (i < n) ? cnt[i] : 0;
    lds[threadIdx.x] = v;
    __syncthreads();
    int acc = v;
#pragma unroll
    for (int o = 1; o < 256; o <<= 1) {
        int t = (threadIdx.x >= o) ? lds[threadIdx.x - o] : 0;
        __syncthreads();
        acc += t;
        lds[threadIdx.x] = acc;
        __syncthreads();
    }
    if (i < n) offs[i] = acc - v;
    if (threadIdx.x == 255) bsum[blockIdx.x] = acc;
}

__global__ __launch_bounds__(512) void csr_scan2(int* __restrict__ bsum, int nb) {
    __shared__ int lds[512];
    const int t = threadIdx.x;
    int v = (t < nb) ? bsum[t] : 0;
    lds[t] = v;
    __syncthreads();
    int acc = v;
#pragma unroll
    for (int o = 1; o < 512; o <<= 1) {
        int x = (t >= o) ? lds[t - o] : 0;
        __syncthreads();
        acc += x;
        lds[t] = acc;
        __syncthreads();
    }
    if (t < nb) bsum[t] = acc - v;
}

__global__ __launch_bounds__(256) void csr_scan3(int* __restrict__ offs,
                                                 const int* __restrict__ bsum,
                                                 int* __restrict__ cur, int n, int total) {
    const int i = blockIdx.x * 256 + threadIdx.x;
    if (i < n) {
        const int o = offs[i] + bsum[blockIdx.x];
        offs[i] = o;
        cur[i] = o;
    }
    if (i == 0) offs[n] = total;
}

__global__ __launch_bounds__(256) void csr_scatter(const int* __restrict__ src,
                                                   const int* __restrict__ dst,
                                                   int* __restrict__ cur,
                                                   int* __restrict__ csr, int ne, int n) {
    const int e = blockIdx.x * 256 + threadIdx.x;
    if (e >= ne + n) return;
    int s, d;
    if (e < ne) { s = src[e]; d = dst[e]; } else { s = d = e - ne; }
    const int slot = atomicAdd(&cur[d], 1);
    csr[slot] = s;
}

// ========== aggregation + fused residual-LN epilogue ==========
// Direct exp (|x| bounded by LN'd features * 0.1-scale att vectors -> safe in f32).
// MODE 0 (layer1): v=xt+gat+gb -> LN1 -> LN2 -> write xt f32 + actb bf16.
// MODE 1 (layer2): v=xt+gat+gb -> LN1 -> write actb bf16 only.
template<int MODE>
__global__ __launch_bounds__(256) void aggr_ln_kernel(const int* __restrict__ csr,
                                                      const int* __restrict__ offs,
                                                      const float* __restrict__ a_s,
                                                      const float* __restrict__ a_d,
                                                      const unsigned short* __restrict__ hWb,
                                                      float* __restrict__ xt,
                                                      const float* __restrict__ gbias,
                                                      const float* __restrict__ g1,
                                                      const float* __restrict__ b1,
                                                      const float* __restrict__ g2,
                                                      const float* __restrict__ b2,
                                                      unsigned short* __restrict__ actb, int n) {
    const int d = (blockIdx.x * blockDim.x + threadIdx.x) >> 6;
    const int lane = threadIdx.x & 63;
    if (d >= n) return;
    const int h = lane >> 4;
    const int beg = offs[d], end = offs[d + 1];
    const float ad = a_d[(size_t)d * 4 + h];

    float z = 0.f, ax = 0.f, ay = 0.f;
    for (int c = beg; c < end; c += 64) {
        const int nj = min(64, end - c);
        const int idx = (c + lane < end) ? csr[c + lane] : 0;
        int j = 0;
        for (; j + 1 < nj; j += 2) {
            const int s0 = __shfl(idx, j);
            const int s1 = __shfl(idx, j + 1);
            const float as0 = a_s[(size_t)s0 * 4 + h];
            const float as1 = a_s[(size_t)s1 * 4 + h];
            const unsigned int u0 =
                reinterpret_cast<const unsigned int*>(hWb + (size_t)s0 * 128)[lane];
            const unsigned int u1 =
                reinterpret_cast<const unsigned int*>(hWb + (size_t)s1 * 128)[lane];
            float x0 = as0 + ad; x0 = x0 > 0.f ? x0 : NEG_SLOPE * x0;
            float x1 = as1 + ad; x1 = x1 > 0.f ? x1 : NEG_SLOPE * x1;
            const float p0 = __expf(x0);
            const float p1 = __expf(x1);
            z += p0 + p1;
            ax += p0 * bf2f_lo(u0) + p1 * bf2f_lo(u1);
            ay += p0 * bf2f_hi(u0) + p1 * bf2f_hi(u1);
        }
        if (j < nj) {
            const int s0 = __shfl(idx, j);
            float x0 = a_s[(size_t)s0 * 4 + h] + ad;
            x0 = x0 > 0.f ? x0 : NEG_SLOPE * x0;
            const float p0 = __expf(x0);
            const unsigned int u0 =
                reinterpret_cast<const unsigned int*>(hWb + (size_t)s0 * 128)[lane];
            z += p0;
            ax += p0 * bf2f_lo(u0);
            ay += p0 * bf2f_hi(u0);
        }
    }
    const float rz = 1.f / z;

    // ---- fused residual + LN epilogue ----
    const float2 a = reinterpret_cast<const float2*>(xt + (size_t)d * 128)[lane];
    const float2 gb = reinterpret_cast<const float2*>(gbias)[lane];
    float2 v;
    v.x = a.x + ax * rz + gb.x;
    v.y = a.y + ay * rz + gb.y;
    float s = v.x + v.y, sq = v.x * v.x + v.y * v.y;
#pragma unroll
    for (int o = 32; o; o >>= 1) { s += __shfl_xor(s, o); sq += __shfl_xor(sq, o); }
    float mu = s * (1.f / 128.f);
    float rinv = rsqrtf(sq * (1.f / 128.f) - mu * mu + LN_EPS);
    const float2 gg1 = reinterpret_cast<const float2*>(g1)[lane];
    const float2 bb1 = reinterpret_cast<const float2*>(b1)[lane];
    float2 y;
    y.x = (v.x - mu) * rinv * gg1.x + bb1.x;
    y.y = (v.y - mu) * rinv * gg1.y + bb1.y;
    if (MODE == 0) {
        s = y.x + y.y; sq = y.x * y.x + y.y * y.y;
#pragma unroll
        for (int o = 32; o; o >>= 1) { s += __shfl_xor(s, o); sq += __shfl_xor(sq, o); }
        mu = s * (1.f / 128.f);
        rinv = rsqrtf(sq * (1.f / 128.f) - mu * mu + LN_EPS);
        const float2 gg2 = reinterpret_cast<const float2*>(g2)[lane];
        const float2 bb2 = reinterpret_cast<const float2*>(b2)[lane];
        float2 o2;
        o2.x = (y.x - mu) * rinv * gg2.x + bb2.x;
        o2.y = (y.y - mu) * rinv * gg2.y + bb2.y;
        reinterpret_cast<float2*>(xt + (size_t)d * 128)[lane] = o2;
        reinterpret_cast<unsigned int*>(actb + (size_t)d * 128)[lane] =
            f2bf_u(o2.x) | (f2bf_u(o2.y) << 16);
    } else {
        reinterpret_cast<unsigned int*>(actb + (size_t)d * 128)[lane] =
            f2bf_u(y.x) | (f2bf_u(y.y) << 16);
    }
}

// ---------------- head: 64 edges per wave, coalesced indices + store ----------------
__global__ __launch_bounds__(256) void head_kernel(const int* __restrict__ src,
                                                   const int* __restrict__ dst,
                                                   const unsigned short* __restrict__ Asb,
                                                   const unsigned short* __restrict__ Adb,
                                                   const float* __restrict__ W2,
                                                   const float* __restrict__ b2,
                                                   float* __restrict__ out, int ne) {
    const int wave = (blockIdx.x * blockDim.x + threadIdx.x) >> 6;
    const int lane = threadIdx.x & 63;
    const int e0 = wave * 64;
    if (e0 >= ne) return;
    const int nj = min(64, ne - e0);
    const bool valid = (e0 + lane) < ne;
    const int sidx = valid ? src[e0 + lane] : 0;
    const int didx = valid ? dst[e0 + lane] : 0;
    const float2 w = reinterpret_cast<const float2*>(W2)[lane];
    const float bb = b2[0];
    float outv = 0.f;
    for (int j = 0; j < nj; ++j) {
        const int s = __shfl(sidx, j);
        const int d = __shfl(didx, j);
        const unsigned int ua =
            reinterpret_cast<const unsigned int*>(Asb + (size_t)s * 128)[lane];
        const unsigned int ub =
            reinterpret_cast<const unsigned int*>(Adb + (size_t)d * 128)[lane];
        float h0 = bf2f_lo(ua) + bf2f_lo(ub); h0 = fmaxf(h0, 0.f);
        float h1 = bf2f_hi(ua) + bf2f_hi(ub); h1 = fmaxf(h1, 0.f);
        float t = h0 * w.x + h1 * w.y;
#pragma unroll
        for (int o = 32; o; o >>= 1) t += __shfl_xor(t, o);
        if (lane == j) outv = t + bb;
    }
    if (valid) out[e0 + lane] = outv;
}

extern "C" void kernel_launch(void* const* d_in, const int* in_sizes, int n_in,
                              void* d_out, int out_size, void* d_ws, size_t ws_size,
                              hipStream_t stream) {
    const int N = NNODES, E = NEDGES;
    const float* x  = (const float*)d_in[0];
    const int* ei   = (const int*)d_in[1];
    const int* src  = ei;
    const int* dst  = ei + E;
    const float* Wp = (const float*)d_in[3];
    const float* bp = (const float*)d_in[4];
    const float* W1 = (const float*)d_in[5];
    const float* b1 = (const float*)d_in[6];
    const float* W2 = (const float*)d_in[7];
    const float* b2 = (const float*)d_in[8];
    const float* l1_ln_a_g = (const float*)d_in[9];
    const float* l1_ln_a_b = (const float*)d_in[10];
    const float* gW1  = (const float*)d_in[11];
    const float* gas1 = (const float*)d_in[12];
    const float* gad1 = (const float*)d_in[13];
    const float* gb1  = (const float*)d_in[14];
    const float* l1_ln_b_g = (const float*)d_in[15];
    const float* l1_ln_b_b = (const float*)d_in[16];
    const float* l2_ln_a_g = (const float*)d_in[17];
    const float* l2_ln_a_b = (const float*)d_in[18];
    const float* gW2  = (const float*)d_in[19];
    const float* gas2 = (const float*)d_in[20];
    const float* gad2 = (const float*)d_in[21];
    const float* gb2  = (const float*)d_in[22];
    const float* l2_ln_b_g = (const float*)d_in[23];
    const float* l2_ln_b_b = (const float*)d_in[24];

    float* ws = (float*)d_ws;
    float* h    = ws;                     // [N,128] f32 (proj out)
    float* xt   = h + (size_t)N * 128;    // [N,128] f32 (residual trunk)
    float* a_s  = xt + (size_t)N * 128;   // [N,4]
    float* a_d  = a_s + (size_t)N * 4;
    unsigned short* actb = (unsigned short*)(a_d + (size_t)N * 4); // [N,128] bf16
    unsigned short* hWb  = actb + (size_t)N * 128;  // [N,128] bf16
    unsigned short* Asb  = hWb + (size_t)N * 128;   // [N,128] bf16
    unsigned short* Adb  = Asb + (size_t)N * 128;   // [N,128] bf16
    unsigned short* BtP  = Adb + (size_t)N * 128;   // [128][832]
    unsigned short* BtG1 = BtP + 128 * KPAD;
    unsigned short* BtG2 = BtG1 + 128 * 128;
    unsigned short* Bt1a = BtG2 + 128 * 128;
    unsigned short* Bt1b = Bt1a + 128 * 128;
    int* cnt  = (int*)(Bt1b + 128 * 128);
    int* offs = cnt + N;
    int* bsum = offs + N + 1;
    int* csr  = bsum + 512;

    const int gemmGrid = (N + 127) / 128;
    const int lnGrid = (N + 3) / 4;
    const int edgeTot = E + N;
    const int edgeGrid = (edgeTot + 255) / 256;
    const int scanBlocks = (N + 255) / 256;
    const int aggrGrid = (N * 64 + 255) / 256;
    const int headWaves = (E + 63) / 64;
    const int headGrid = (headWaves + 3) / 4;
    const int setupTot = 128 * KPAD + 4 * 128 * 128 + N;

    setup_kernel<<<(setupTot + 255) / 256, 256, 0, stream>>>(Wp, gW1, gW2, W1, BtP, BtG1,
                                                             BtG2, Bt1a, Bt1b, cnt);
    csr_hist<<<edgeGrid, 256, 0, stream>>>(dst, cnt, E, N);
    csr_scan1<<<scanBlocks, 256, 0, stream>>>(cnt, offs, bsum, N);
    csr_scan2<<<1, 512, 0, stream>>>(bsum, scanBlocks);
    csr_scan3<<<scanBlocks, 256, 0, stream>>>(offs, bsum, cnt, N, edgeTot);
    csr_scatter<<<edgeGrid, 256, 0, stream>>>(src, dst, cnt, csr, E, N);

    // ---- input projection + first LN
    gemm_proj<<<gemmGrid, 256, 0, stream>>>(x, BtP, bp, h, N);
    ln_kernel<<<lnGrid, 256, 0, stream>>>(h, l1_ln_a_g, l1_ln_a_b, xt, actb, N);

    // ---- layer 1: GEMM(+asad) -> aggr(+LN_b1+LN_a2)
    gemm_k128<true, false><<<gemmGrid, 256, 0, stream>>>(actb, BtG1, nullptr, gas1, gad1,
                                                         hWb, a_s, a_d, N);
    aggr_ln_kernel<0><<<aggrGrid, 256, 0, stream>>>(csr, offs, a_s, a_d, hWb, xt, gb1,
                                                    l1_ln_b_g, l1_ln_b_b, l2_ln_a_g,
                                                    l2_ln_a_b, actb, N);
    // ---- layer 2
    gemm_k128<true, false><<<gemmGrid, 256, 0, stream>>>(actb, BtG2, nullptr, gas2, gad2,
                                                         hWb, a_s, a_d, N);
    aggr_ln_kernel<1><<<aggrGrid, 256, 0, stream>>>(csr, offs, a_s, a_d, hWb, xt, gb2,
                                                    l2_ln_b_g, l2_ln_b_b, nullptr,
                                                    nullptr, actb, N);

    // ---- head: two K=128 GEMMs sharing A (actb) -> bf16 As/Ad, then per-edge MLP
    gemm_k128<false, true><<<gemmGrid, 256, 0, stream>>>(actb, Bt1a, b1, nullptr, nullptr,
                                                         Asb, nullptr, nullptr, N);
    gemm_k128<false, false><<<gemmGrid, 256, 0, stream>>>(actb, Bt1b, nullptr, nullptr,
                                                          nullptr, Adb, nullptr, nullptr, N);
    head_kernel<<<headGrid, 256, 0, stream>>>(src, dst, Asb, Adb, W2, b2,
                                              (float*)d_out, E);
}